// Round 2
// baseline (94.912 us; speedup 1.0000x reference)
//
#include <hip/hip_runtime.h>
#include <cmath>
#include <cstdint>

// Problem: B=2, C=32, Z=4, E=2, N=4096. One candidate point per lattice cell,
// cell pitch (0.78125, 0.78125, 0.75); offsets in [0,1) cell units.
// => dist < ele_d (0.74 / 0.528) pairs confined to 3x3x3 cells.
// => any point outside the xy +-2 window is >= 1.5625*(1-eps) away: a
//    neighborhood argmin < GUARD=1.4999 is provably the global argmin.
//
// Structure (1 kernel, was 4 -> 2 -> 1): session is epoch/fill-bound, our
// compute is ~5us on L2-resident 0.5MB inputs. Each block owns a
// (s, gx, 16-gy-slab) interior of 64 rows and computes restrain over a
// 7x22x4 LDS halo, keep over 5x20x4, then match — no workspace, no second
// launch, no grid sync. Halo recompute is ~0.5us/block-set, cheaper than a
// launch node (~1us measured R0->R1).
namespace {
constexpr int NPT  = 4096;

// output offsets (floats), reference return order
constexpr int O_PPOS  = 0;
constexpr int O_MASKP = 49152;
constexpr int O_KEEP  = 65536;
constexpr int O_TPOS  = 81920;
constexpr int O_MASKT = 131072;
constexpr int O_TPT   = 147456;
constexpr int O_TPP   = 163840;
constexpr int O_TPTN  = 180224;
constexpr int O_TPPN  = 196608;

constexpr float GUARD = 1.4999f;
} // namespace

__device__ __forceinline__ unsigned long long shfl_xor_u64(unsigned long long v, int m) {
    unsigned lo = (unsigned)v, hi = (unsigned)(v >> 32);
    lo = __shfl_xor(lo, m); hi = __shfl_xor(hi, m);
    return ((unsigned long long)hi << 32) | lo;
}

// position from raw input + cell index — bit-identical everywhere (contract off,
// lattice constants 25/32 and 3/4 are exactly representable)
__device__ __forceinline__ float3 cellpos(float4 p, int n) {
#pragma clang fp contract(off)
    float fx = (float)(n >> 7), fy = (float)((n >> 2) & 31), fz = (float)(n & 3);
    float3 r;
    r.x = (p.x + fx) * 0.78125f;
    r.y = (p.y + fy) * 0.78125f;
    r.z = (p.z + fz) * 0.75f;
    return r;
}
__device__ __forceinline__ float dist2(float3 a, float3 b) {
#pragma clang fp contract(off)
    float dx = a.x - b.x, dy = a.y - b.y, dz = a.z - b.z;
    float d2 = dx * dx + dy * dy;
    return d2 + dz * dz;   // numpy sum order: (x+y)+z
}

// exact restrain count of slice-local point pn (reference: column sums of
// triu-adjacency restricted to valid pairs). Used by the LDS phase and by the
// never-taken exact fallback.
__device__ __forceinline__ unsigned restrain_of(const float4* __restrict__ pred,
                                                int base4, int pn, float se) {
#pragma clang fp contract(off)
    float4 p = pred[base4 + pn * 2];
    if (!(p.w > 0.5f)) return 0u;
    float3 pj = cellpos(p, pn);
    int gx = pn >> 7, gy = (pn >> 2) & 31;
    unsigned c = 0;
    for (int q = 0; q < 9; ++q) {
        int nx = gx + q / 3 - 1, ny = gy + q % 3 - 1;
        if ((unsigned)nx > 31u || (unsigned)ny > 31u) continue;
        int nb = nx * 128 + ny * 4;
#pragma unroll
        for (int nz = 0; nz < 4; ++nz) {
            int ni = nb + nz;
            float4 pi = pred[base4 + ni * 2];
            float3 qi = cellpos(pi, ni);
            float d2 = dist2(pj, qi);
            bool prec = (pi.w > p.w) || ((pi.w == p.w) && (ni < pn));
            if ((pi.w > 0.5f) && (d2 < se) && prec) c++;
        }
    }
    return c;
}

// exact keep decision of slice-local point k (suppression step on top of
// restrain). Only called from the rare fallback path.
__device__ __noinline__ bool keep_of(const float4* __restrict__ pred,
                                     int base4, int k, float se) {
#pragma clang fp contract(off)
    float4 p = pred[base4 + k * 2];
    if (!(p.w > 0.5f)) return false;
    float3 pj = cellpos(p, k);
    int gx = k >> 7, gy = (k >> 2) & 31;
    for (int q = 0; q < 9; ++q) {
        int nx = gx + q / 3 - 1, ny = gy + q % 3 - 1;
        if ((unsigned)nx > 31u || (unsigned)ny > 31u) continue;
        int nb = nx * 128 + ny * 4;
        for (int nz = 0; nz < 4; ++nz) {
            int ni = nb + nz;
            float4 pi = pred[base4 + ni * 2];
            float3 qi = cellpos(pi, ni);
            float d2 = dist2(pj, qi);
            bool prec = (pi.w > p.w) || ((pi.w == p.w) && (ni < k));
            if ((pi.w > 0.5f) && (d2 < se) && prec &&
                restrain_of(pred, base4, ni, se) == 0u)
                return false;
        }
    }
    return true;
}

// ---------------------------------------------------------------------------
// Single fused kernel. One block per (s, gx, gy-half): 4*32*2 = 256 blocks.
// Phase A: restrain counts over the [gx-3,gx+3]x[gy0-3,gy0+18]x[0,4) halo -> LDS.
// Phase B: keep over [gx-2,gx+2]x[gy0-2,gy0+17]x[0,4) -> LDS; interior points
//          (x==gx, y in slab) write p_pos / mask_p / keep outputs.
// Phase C: match (both variants) for the 64 interior rows, 4 threads/row,
//          5x5 xy window x full z, keep from LDS, inline exact fallback.
__global__ void __launch_bounds__(256) k_all(const float4* __restrict__ pred,
                                             const float4* __restrict__ tgt,
                                             float* __restrict__ out,
                                             float s0, float s1) {
#pragma clang fp contract(off)
    __shared__ unsigned char restr[7 * 22 * 4];   // [rx 7][ry 22][z 4] = 616
    __shared__ unsigned char keepl[5 * 20 * 4];   // [kx 5][ky 20][z 4] = 400
    int bid = blockIdx.x;
    int h2 = bid & 1, gx = (bid >> 1) & 31, s = bid >> 6;
    int b = s >> 1, e = s & 1;
    int base4 = b * 8192 + e;
    float se = (s & 1) ? s1 : s0;
    int gy0 = h2 << 4;
    int t = (int)threadIdx.x;

    // ---- phase A: restrain halo (616 pts, <=3 per thread)
    for (int ra = t; ra < 616; ra += 256) {
        int rx = ra / 88, rem = ra - rx * 88, ry = rem >> 2, z = rem & 3;
        int px = gx + rx - 3, py = gy0 + ry - 3;
        unsigned c = 0;
        if ((unsigned)px < 32u && (unsigned)py < 32u)
            c = restrain_of(pred, base4, px * 128 + py * 4 + z, se);
        restr[ra] = (unsigned char)c;             // max 36, fits uchar
    }
    __syncthreads();

    // ---- phase B: keep halo (400 pts, <=2 per thread); interior writes out
    for (int kb = t; kb < 400; kb += 256) {
        int kx = kb / 80, rem = kb - kx * 80, ky = rem >> 2, z = rem & 3;
        int px = gx + kx - 2, py = gy0 + ky - 2;
        bool keep = false;
        bool interior = (kx == 2) && (ky >= 2) && (ky < 18);
        if ((unsigned)px < 32u && (unsigned)py < 32u) {
            int pn = px * 128 + py * 4 + z;
            float4 p = pred[base4 + pn * 2];
            float3 pj = cellpos(p, pn);
            bool valid = p.w > 0.5f;
            unsigned any = 0;
            if (valid) {
                for (int q = 0; q < 9; ++q) {
                    int dx = q / 3 - 1, dy = q % 3 - 1;
                    int nx = px + dx, ny = py + dy;
                    if ((unsigned)nx > 31u || (unsigned)ny > 31u) continue;
                    int nb = nx * 128 + ny * 4;
                    const unsigned char* lr =
                        &restr[((kx + dx + 1) * 22 + (ky + dy + 1)) * 4];
#pragma unroll
                    for (int nz = 0; nz < 4; ++nz) {
                        int ni = nb + nz;
                        float4 pi = pred[base4 + ni * 2];
                        float3 qi = cellpos(pi, ni);
                        float d2 = dist2(pj, qi);
                        bool prec = (pi.w > p.w) || ((pi.w == p.w) && (ni < pn));
                        bool flg = (pi.w > 0.5f) && (lr[nz] == 0);
                        if (flg && (d2 < se) && prec) any = 1u;
                    }
                }
            }
            keep = valid && !any;
            if (interior) {
                int row = s * NPT + pn;
                out[O_PPOS + row * 3 + 0] = pj.x;
                out[O_PPOS + row * 3 + 1] = pj.y;
                out[O_PPOS + row * 3 + 2] = pj.z;
                out[O_MASKP + row] = valid ? 1.0f : 0.0f;
                out[O_KEEP + row] = keep ? 1.0f : 0.0f;
            }
        }
        keepl[kb] = keep ? 1 : 0;
    }
    __syncthreads();

    // ---- phase C: match, 64 rows x 4 threads
    int r = t >> 2, h = t & 3;
    int gy = gy0 + (r >> 2), z = r & 3;
    int n = (gx << 7) + (gy << 2) + z;
    int row = s * NPT + n;
    float4 t4 = tgt[base4 + n * 2];
    float3 tj = cellpos(t4, n);
    bool tv = t4.w > 0.5f;
    if (h == 0) {
        out[O_TPOS + row * 3 + 0] = tj.x;
        out[O_TPOS + row * 3 + 1] = tj.y;
        out[O_TPOS + row * 3 + 2] = tj.z;
        out[O_MASKT + row] = tv ? 1.0f : 0.0f;
    }
    if (!tv) {   // quad-uniform early out (all-inf row -> masks 0, idx 0)
        if (h == 0) {
            out[O_TPT + row] = 0.0f; out[O_TPTN + row] = 0.0f;
            out[O_TPP + row] = 0.0f; out[O_TPPN + row] = 0.0f;
        }
        return;
    }
    unsigned long long bs = ~0ull, bn = ~0ull;
    unsigned as_ = 0, an_ = 0;
    for (int qq = 0; qq < 7; ++qq) {
        int q = qq * 4 + h;                      // h=0 gets 7 cells, others 6
        if (q > 24) continue;
        int dx = q / 5 - 2, dy = q % 5 - 2;
        int nx = gx + dx, ny = gy + dy;
        if ((unsigned)nx > 31u || (unsigned)ny > 31u) continue;
        int nb = nx * 128 + ny * 4;
        const unsigned char* lk =
            &keepl[((dx + 2) * 20 + (gy - gy0 + dy + 2)) * 4];
#pragma unroll
        for (int nz = 0; nz < 4; ++nz) {
            int ni = nb + nz;
            float4 pi = pred[base4 + ni * 2];
            float3 qi = cellpos(pi, ni);
            float d2 = dist2(tj, qi);
            float dist = sqrtf(d2);
            unsigned long long enc =
                ((unsigned long long)__float_as_uint(dist) << 32) | (unsigned)ni;
            if (pi.w > 0.5f) { if (enc < bs) bs = enc; if (d2 < se) as_ = 1u; }
            if (lk[nz]) { if (enc < bn) bn = enc; if (d2 < se) an_ = 1u; }
        }
    }
    for (int m = 1; m < 4; m <<= 1) {            // combine across the row-quad
        unsigned long long o = shfl_xor_u64(bs, m); if (o < bs) bs = o;
        o = shfl_xor_u64(bn, m); if (o < bn) bn = o;
        as_ |= __shfl_xor(as_, m);
        an_ |= __shfl_xor(an_, m);
    }
    // empty best -> hi word 0xFFFFFFFF = NaN -> compare false -> fallback
    bool acc_s = __uint_as_float((unsigned)(bs >> 32)) < GUARD;
    bool acc_n = __uint_as_float((unsigned)(bn >> 32)) < GUARD;
    if (!(acc_s && acc_n)) {
        // exact full-row fallback by this quad (p ~ 1e-11, never observed;
        // bit-equal to window result when the window would have accepted).
        // keep recomputed on the fly, pruned to improving candidates only.
        unsigned long long fs = ~0ull, fn = ~0ull;
        for (int k = h; k < NPT; k += 4) {
            float4 pi = pred[base4 + k * 2];
            float3 qi = cellpos(pi, k);
            float d2 = dist2(tj, qi);
            float dist = sqrtf(d2);
            unsigned long long enc =
                ((unsigned long long)__float_as_uint(dist) << 32) | (unsigned)k;
            if (pi.w > 0.5f && enc < fs) fs = enc;
            if (enc < fn && keep_of(pred, base4, k, se)) fn = enc;
        }
        for (int m = 1; m < 4; m <<= 1) {
            unsigned long long o = shfl_xor_u64(fs, m); if (o < fs) fs = o;
            o = shfl_xor_u64(fn, m); if (o < fn) fn = o;
        }
        bs = fs; bn = fn;
    }
    if (h == 0) {
        out[O_TPT + row]  = as_ ? 1.0f : 0.0f;
        out[O_TPTN + row] = an_ ? 1.0f : 0.0f;
        out[O_TPP + row]  = (float)((bs == ~0ull) ? 0u : (unsigned)(bs & 0xffffffffull));
        out[O_TPPN + row] = (float)((bn == ~0ull) ? 0u : (unsigned)(bn & 0xffffffffull));
    }
}

// ---------------------------------------------------------------------------
// host: smallest f with sqrtf(f) >= t, so (d2 < f) <=> (sqrtf(d2) < t) bit-exactly.
static float sq_boundary(float t) {
    float f = (float)((double)t * (double)t);
    while (sqrtf(f) >= t) f = nextafterf(f, 0.0f);
    while (sqrtf(f) < t)  f = nextafterf(f, __builtin_inff());
    return f;
}

extern "C" void kernel_launch(void* const* d_in, const int* in_sizes, int n_in,
                              void* d_out, int out_size, void* d_ws, size_t ws_size,
                              hipStream_t stream) {
    (void)in_sizes; (void)n_in; (void)out_size; (void)d_ws; (void)ws_size;
    const float4* pred = (const float4*)d_in[0];
    const float4* tgt  = (const float4*)d_in[1];
    float* out = (float*)d_out;

    float s0 = sq_boundary(0.74f);    // ELE_D[0]
    float s1 = sq_boundary(0.528f);   // ELE_D[1]

    k_all<<<dim3(256), dim3(256), 0, stream>>>(pred, tgt, out, s0, s1);
}

// Round 3
// 70.004 us; speedup vs baseline: 1.3558x; 1.3558x over previous
//
#include <hip/hip_runtime.h>
#include <cmath>
#include <cstdint>

// Problem: B=2, C=32, Z=4, E=2, N=4096. One candidate point per lattice cell,
// cell pitch (0.78125, 0.78125, 0.75); offsets in [0,1) cell units.
// => dist < ele_d (0.74 / 0.528) pairs confined to 3x3x3 cells.
// => any point outside the xy +-2 window is >= 1.5625*(1-eps) away: a
//    neighborhood argmin < GUARD=1.4999 is provably the global argmin.
//
// R2 lesson: the fused kernel was 44.5us because every dist-comp loaded
// pred[] from L1/L2 in serial per-thread loops at 1 wave/SIMD (VALUBusy 17%,
// HBM 0.5% -> latency-bound). R3: stage the block's 9x24x4 pred window into
// LDS ONCE (position pre-projected, conf in .w, OOB as conf=-1 so all
// predicates reject it branch-free), run restrain/keep/match phases entirely
// from LDS, 512 threads (2 waves/SIMD). VALU roofline ~4us.
namespace {
constexpr int NPT  = 4096;

// output offsets (floats), reference return order
constexpr int O_PPOS  = 0;
constexpr int O_MASKP = 49152;
constexpr int O_KEEP  = 65536;
constexpr int O_TPOS  = 81920;
constexpr int O_MASKT = 131072;
constexpr int O_TPT   = 147456;
constexpr int O_TPP   = 163840;
constexpr int O_TPTN  = 180224;
constexpr int O_TPPN  = 196608;

constexpr float GUARD = 1.4999f;
} // namespace

__device__ __forceinline__ unsigned long long shfl_xor_u64(unsigned long long v, int m) {
    unsigned lo = (unsigned)v, hi = (unsigned)(v >> 32);
    lo = __shfl_xor(lo, m); hi = __shfl_xor(hi, m);
    return ((unsigned long long)hi << 32) | lo;
}

// position from raw input + cell index — bit-identical everywhere (contract off,
// lattice constants 25/32 and 3/4 are exactly representable)
__device__ __forceinline__ float3 cellpos(float4 p, int n) {
#pragma clang fp contract(off)
    float fx = (float)(n >> 7), fy = (float)((n >> 2) & 31), fz = (float)(n & 3);
    float3 r;
    r.x = (p.x + fx) * 0.78125f;
    r.y = (p.y + fy) * 0.78125f;
    r.z = (p.z + fz) * 0.75f;
    return r;
}
__device__ __forceinline__ float dist2(float3 a, float3 b) {
#pragma clang fp contract(off)
    float dx = a.x - b.x, dy = a.y - b.y, dz = a.z - b.z;
    float d2 = dx * dx + dy * dy;
    return d2 + dz * dz;   // numpy sum order: (x+y)+z
}

// exact restrain count of slice-local point pn, reading GLOBAL pred.
// Only used by the never-taken exact fallback.
__device__ __forceinline__ unsigned restrain_of(const float4* __restrict__ pred,
                                                int base4, int pn, float se) {
#pragma clang fp contract(off)
    float4 p = pred[base4 + pn * 2];
    if (!(p.w > 0.5f)) return 0u;
    float3 pj = cellpos(p, pn);
    int gx = pn >> 7, gy = (pn >> 2) & 31;
    unsigned c = 0;
    for (int q = 0; q < 9; ++q) {
        int nx = gx + q / 3 - 1, ny = gy + q % 3 - 1;
        if ((unsigned)nx > 31u || (unsigned)ny > 31u) continue;
        int nb = nx * 128 + ny * 4;
#pragma unroll
        for (int nz = 0; nz < 4; ++nz) {
            int ni = nb + nz;
            float4 pi = pred[base4 + ni * 2];
            float3 qi = cellpos(pi, ni);
            float d2 = dist2(pj, qi);
            bool prec = (pi.w > p.w) || ((pi.w == p.w) && (ni < pn));
            if ((pi.w > 0.5f) && (d2 < se) && prec) c++;
        }
    }
    return c;
}

// exact keep decision of slice-local point k (suppression on top of restrain),
// reading GLOBAL pred. Only called from the rare fallback path.
__device__ __noinline__ bool keep_of(const float4* __restrict__ pred,
                                     int base4, int k, float se) {
#pragma clang fp contract(off)
    float4 p = pred[base4 + k * 2];
    if (!(p.w > 0.5f)) return false;
    float3 pj = cellpos(p, k);
    int gx = k >> 7, gy = (k >> 2) & 31;
    for (int q = 0; q < 9; ++q) {
        int nx = gx + q / 3 - 1, ny = gy + q % 3 - 1;
        if ((unsigned)nx > 31u || (unsigned)ny > 31u) continue;
        int nb = nx * 128 + ny * 4;
        for (int nz = 0; nz < 4; ++nz) {
            int ni = nb + nz;
            float4 pi = pred[base4 + ni * 2];
            float3 qi = cellpos(pi, ni);
            float d2 = dist2(pj, qi);
            bool prec = (pi.w > p.w) || ((pi.w == p.w) && (ni < k));
            if ((pi.w > 0.5f) && (d2 < se) && prec &&
                restrain_of(pred, base4, ni, se) == 0u)
                return false;
        }
    }
    return true;
}

// ---------------------------------------------------------------------------
// Single fused kernel. One block per (s, gx, gy-half): 4*32*2 = 256 blocks,
// 512 threads (8 waves -> 2 waves/SIMD at 1 block/CU).
// Stage : pred window [gx-4,gx+4] x [gy0-4,gy0+19] x z  (9x24x4=864) -> LDS,
//         position pre-projected, conf in .w; OOB cells get conf=-1 which
//         every later predicate rejects, so phase loops are bounds-check-free.
// Phase A: restrain over [gx-3..+3] x [gy0-3..+18] (7x22x4=616) -> LDS uchar.
// Phase B: keep over [gx-2..+2] x [gy0-2..+17] (5x20x4=400) -> LDS uchar;
//          interior 64 rows write p_pos / mask_p / keep.
// Phase C: match (both variants) for the 64 interior rows, 8 threads/row,
//          5x5 xy window x full z from LDS, inline exact (global) fallback.
__global__ void __launch_bounds__(512) k_all(const float4* __restrict__ pred,
                                             const float4* __restrict__ tgt,
                                             float* __restrict__ out,
                                             float s0, float s1) {
#pragma clang fp contract(off)
    __shared__ float4 pp[9 * 24 * 4];             // (pos.xyz, conf) 13824 B
    __shared__ unsigned char restr[7 * 22 * 4];   // 616
    __shared__ unsigned char keepl[5 * 20 * 4];   // 400
    int bid = blockIdx.x;
    int h2 = bid & 1, gx = (bid >> 1) & 31, s = bid >> 6;
    int b = s >> 1, e = s & 1;
    int base4 = b * 8192 + e;
    float se = (s & 1) ? s1 : s0;
    int gy0 = h2 << 4;
    int t = (int)threadIdx.x;

    // ---- stage pred window -> LDS (<=2 coalesced-ish loads per thread)
    for (int i = t; i < 864; i += 512) {
        int rx = i / 96, rem = i - rx * 96, ry = rem >> 2, z = rem & 3;
        int px = gx + rx - 4, py = gy0 + ry - 4;
        float4 v = {0.0f, 0.0f, 0.0f, -1.0f};
        if ((unsigned)px < 32u && (unsigned)py < 32u) {
            int pn = px * 128 + py * 4 + z;
            float4 p = pred[base4 + pn * 2];
            float3 c = cellpos(p, pn);
            v.x = c.x; v.y = c.y; v.z = c.z; v.w = p.w;
        }
        pp[i] = v;
    }
    __syncthreads();

    // ---- phase A: restrain halo (616 pts)
    for (int ra = t; ra < 616; ra += 512) {
        int ax = ra / 88, rem = ra - ax * 88, ay = rem >> 2, z = rem & 3;
        int px = gx + ax - 3, py = gy0 + ay - 3;
        float4 p = pp[((ax + 1) * 24 + (ay + 1)) * 4 + z];
        unsigned c = 0;
        if (p.w > 0.5f) {                          // OOB center: conf=-1 -> skip
            int pn = px * 128 + py * 4 + z;
            float3 pj = {p.x, p.y, p.z};
            for (int q = 0; q < 9; ++q) {
                int dx = q / 3 - 1, dy = q % 3 - 1;
                int nb = (px + dx) * 128 + (py + dy) * 4;
                const float4* pc = &pp[((ax + 1 + dx) * 24 + (ay + 1 + dy)) * 4];
#pragma unroll
                for (int nz = 0; nz < 4; ++nz) {
                    float4 pi = pc[nz];
                    int ni = nb + nz;
                    float3 qi = {pi.x, pi.y, pi.z};
                    float d2 = dist2(pj, qi);
                    bool prec = (pi.w > p.w) || ((pi.w == p.w) && (ni < pn));
                    if ((pi.w > 0.5f) && (d2 < se) && prec) c++;
                }
            }
        }
        restr[ra] = (unsigned char)c;              // max 36, fits uchar
    }
    __syncthreads();

    // ---- phase B: keep halo (400 pts); interior writes outputs
    for (int kb = t; kb < 400; kb += 512) {
        int kx = kb / 80, rem = kb - kx * 80, ky = rem >> 2, z = rem & 3;
        int px = gx + kx - 2, py = gy0 + ky - 2;
        float4 p = pp[((kx + 2) * 24 + (ky + 2)) * 4 + z];
        bool valid = p.w > 0.5f;
        int pn = px * 128 + py * 4 + z;
        unsigned any = 0;
        if (valid) {
            float3 pj = {p.x, p.y, p.z};
            for (int q = 0; q < 9; ++q) {
                int dx = q / 3 - 1, dy = q % 3 - 1;
                int nb = (px + dx) * 128 + (py + dy) * 4;
                const float4* pc = &pp[((kx + 2 + dx) * 24 + (ky + 2 + dy)) * 4];
                const unsigned char* lr =
                    &restr[((kx + 1 + dx) * 22 + (ky + 1 + dy)) * 4];
#pragma unroll
                for (int nz = 0; nz < 4; ++nz) {
                    float4 pi = pc[nz];
                    int ni = nb + nz;
                    float3 qi = {pi.x, pi.y, pi.z};
                    float d2 = dist2(pj, qi);
                    bool prec = (pi.w > p.w) || ((pi.w == p.w) && (ni < pn));
                    if ((pi.w > 0.5f) && (lr[nz] == 0) && (d2 < se) && prec) any = 1u;
                }
            }
        }
        bool keep = valid && (any == 0);
        keepl[kb] = keep ? 1 : 0;
        if (kx == 2 && ky >= 2 && ky < 18) {       // interior: always in-bounds
            int row = s * NPT + pn;
            out[O_PPOS + row * 3 + 0] = p.x;
            out[O_PPOS + row * 3 + 1] = p.y;
            out[O_PPOS + row * 3 + 2] = p.z;
            out[O_MASKP + row] = valid ? 1.0f : 0.0f;
            out[O_KEEP + row]  = keep ? 1.0f : 0.0f;
        }
    }
    __syncthreads();

    // ---- phase C: match, 64 rows x 8 threads
    int r = t >> 3, h = t & 7;
    int gyy = r >> 2, z = r & 3;
    int gy = gy0 + gyy;
    int n = (gx << 7) + (gy << 2) + z;
    int row = s * NPT + n;
    float4 t4 = tgt[base4 + n * 2];
    float3 tj = cellpos(t4, n);
    bool tv = t4.w > 0.5f;
    if (h == 0) {
        out[O_TPOS + row * 3 + 0] = tj.x;
        out[O_TPOS + row * 3 + 1] = tj.y;
        out[O_TPOS + row * 3 + 2] = tj.z;
        out[O_MASKT + row] = tv ? 1.0f : 0.0f;
    }
    if (!tv) {   // group-uniform early out (all-inf row -> masks 0, idx 0)
        if (h == 0) {
            out[O_TPT + row] = 0.0f; out[O_TPTN + row] = 0.0f;
            out[O_TPP + row] = 0.0f; out[O_TPPN + row] = 0.0f;
        }
        return;
    }
    unsigned long long bs = ~0ull, bn = ~0ull;
    unsigned as_ = 0, an_ = 0;
    for (int qq = 0; qq < 4; ++qq) {
        int q = qq * 8 + h;                        // h=0 gets 4 cells, others 3
        if (q > 24) continue;
        int dx = q / 5 - 2, dy = q % 5 - 2;
        int nb = (gx + dx) * 128 + (gy + dy) * 4;
        const float4* pc = &pp[((dx + 4) * 24 + (gyy + dy + 4)) * 4];
        const unsigned char* lk = &keepl[((dx + 2) * 20 + (gyy + dy + 2)) * 4];
#pragma unroll
        for (int nz = 0; nz < 4; ++nz) {
            float4 pi = pc[nz];
            int ni = nb + nz;
            float3 qi = {pi.x, pi.y, pi.z};
            float d2 = dist2(tj, qi);
            float dist = sqrtf(d2);
            unsigned long long enc =
                ((unsigned long long)__float_as_uint(dist) << 32) | (unsigned)ni;
            if (pi.w > 0.5f) { if (enc < bs) bs = enc; if (d2 < se) as_ = 1u; }
            if (lk[nz]) { if (enc < bn) bn = enc; if (d2 < se) an_ = 1u; }
        }
    }
    for (int m = 1; m < 8; m <<= 1) {              // combine across the 8-group
        unsigned long long o = shfl_xor_u64(bs, m); if (o < bs) bs = o;
        o = shfl_xor_u64(bn, m); if (o < bn) bn = o;
        as_ |= __shfl_xor(as_, m);
        an_ |= __shfl_xor(an_, m);
    }
    // empty best -> hi word 0xFFFFFFFF = NaN -> compare false -> fallback
    bool acc_s = __uint_as_float((unsigned)(bs >> 32)) < GUARD;
    bool acc_n = __uint_as_float((unsigned)(bn >> 32)) < GUARD;
    if (!(acc_s && acc_n)) {
        // exact full-row fallback by this 8-group (p ~ 1e-11, never observed;
        // bit-equal to window result when the window would have accepted).
        unsigned long long fs = ~0ull, fn = ~0ull;
        for (int k = h; k < NPT; k += 8) {
            float4 pi = pred[base4 + k * 2];
            float3 qi = cellpos(pi, k);
            float d2 = dist2(tj, qi);
            float dist = sqrtf(d2);
            unsigned long long enc =
                ((unsigned long long)__float_as_uint(dist) << 32) | (unsigned)k;
            if (pi.w > 0.5f && enc < fs) fs = enc;
            if (enc < fn && keep_of(pred, base4, k, se)) fn = enc;
        }
        for (int m = 1; m < 8; m <<= 1) {
            unsigned long long o = shfl_xor_u64(fs, m); if (o < fs) fs = o;
            o = shfl_xor_u64(fn, m); if (o < fn) fn = o;
        }
        bs = fs; bn = fn;
    }
    if (h == 0) {
        out[O_TPT + row]  = as_ ? 1.0f : 0.0f;
        out[O_TPTN + row] = an_ ? 1.0f : 0.0f;
        out[O_TPP + row]  = (float)((bs == ~0ull) ? 0u : (unsigned)(bs & 0xffffffffull));
        out[O_TPPN + row] = (float)((bn == ~0ull) ? 0u : (unsigned)(bn & 0xffffffffull));
    }
}

// ---------------------------------------------------------------------------
// host: smallest f with sqrtf(f) >= t, so (d2 < f) <=> (sqrtf(d2) < t) bit-exactly.
static float sq_boundary(float t) {
    float f = (float)((double)t * (double)t);
    while (sqrtf(f) >= t) f = nextafterf(f, 0.0f);
    while (sqrtf(f) < t)  f = nextafterf(f, __builtin_inff());
    return f;
}

extern "C" void kernel_launch(void* const* d_in, const int* in_sizes, int n_in,
                              void* d_out, int out_size, void* d_ws, size_t ws_size,
                              hipStream_t stream) {
    (void)in_sizes; (void)n_in; (void)out_size; (void)d_ws; (void)ws_size;
    const float4* pred = (const float4*)d_in[0];
    const float4* tgt  = (const float4*)d_in[1];
    float* out = (float*)d_out;

    float s0 = sq_boundary(0.74f);    // ELE_D[0]
    float s1 = sq_boundary(0.528f);   // ELE_D[1]

    k_all<<<dim3(256), dim3(512), 0, stream>>>(pred, tgt, out, s0, s1);
}

// Round 4
// 64.848 us; speedup vs baseline: 1.4636x; 1.0795x over previous
//
#include <hip/hip_runtime.h>
#include <cmath>
#include <cstdint>

// Problem: B=2, C=32, Z=4, E=2, N=4096. One candidate point per lattice cell,
// cell pitch (0.78125, 0.78125, 0.75); offsets in [0,1) cell units.
// => dist < ele_d (0.74 / 0.528) pairs confined to 3x3x3 cells.
// => any point outside the xy +-2 window is >= 1.5625*(1-eps) away: a
//    neighborhood argmin < GUARD=1.4999 is provably the global argmin.
// => for NMS adjacency specifically: pairs >=2 z-cells apart have
//    dz >= 0.75*(1-2^-23) => d2 >= 0.5624998 > se(0.74)=0.5476 — so
//    restrain/keep only need z+-1 (fp-safe margin ~3%). Match keeps full z.
//
// R3 lesson: single fused kernel at 1 block/CU (2 waves/SIMD) ran 19.6us at
// VALUBusy ~17% — latency-floored, not work-floored. R4: 512 blocks
// (gy-quarter interior) x 512 threads = 2 blocks/CU, 16 waves/CU; z+-1
// pruning in phases A/B (-25% comps); tgt prefetch at entry.
namespace {
constexpr int NPT  = 4096;

// output offsets (floats), reference return order
constexpr int O_PPOS  = 0;
constexpr int O_MASKP = 49152;
constexpr int O_KEEP  = 65536;
constexpr int O_TPOS  = 81920;
constexpr int O_MASKT = 131072;
constexpr int O_TPT   = 147456;
constexpr int O_TPP   = 163840;
constexpr int O_TPTN  = 180224;
constexpr int O_TPPN  = 196608;

constexpr float GUARD = 1.4999f;
} // namespace

__device__ __forceinline__ unsigned long long shfl_xor_u64(unsigned long long v, int m) {
    unsigned lo = (unsigned)v, hi = (unsigned)(v >> 32);
    lo = __shfl_xor(lo, m); hi = __shfl_xor(hi, m);
    return ((unsigned long long)hi << 32) | lo;
}

// position from raw input + cell index — bit-identical everywhere (contract off,
// lattice constants 25/32 and 3/4 are exactly representable)
__device__ __forceinline__ float3 cellpos(float4 p, int n) {
#pragma clang fp contract(off)
    float fx = (float)(n >> 7), fy = (float)((n >> 2) & 31), fz = (float)(n & 3);
    float3 r;
    r.x = (p.x + fx) * 0.78125f;
    r.y = (p.y + fy) * 0.78125f;
    r.z = (p.z + fz) * 0.75f;
    return r;
}
__device__ __forceinline__ float dist2(float3 a, float3 b) {
#pragma clang fp contract(off)
    float dx = a.x - b.x, dy = a.y - b.y, dz = a.z - b.z;
    float d2 = dx * dx + dy * dy;
    return d2 + dz * dz;   // numpy sum order: (x+y)+z
}

// exact restrain count of slice-local point pn, reading GLOBAL pred.
// Only used by the never-taken exact fallback.
__device__ __forceinline__ unsigned restrain_of(const float4* __restrict__ pred,
                                                int base4, int pn, float se) {
#pragma clang fp contract(off)
    float4 p = pred[base4 + pn * 2];
    if (!(p.w > 0.5f)) return 0u;
    float3 pj = cellpos(p, pn);
    int gx = pn >> 7, gy = (pn >> 2) & 31;
    unsigned c = 0;
    for (int q = 0; q < 9; ++q) {
        int nx = gx + q / 3 - 1, ny = gy + q % 3 - 1;
        if ((unsigned)nx > 31u || (unsigned)ny > 31u) continue;
        int nb = nx * 128 + ny * 4;
#pragma unroll
        for (int nz = 0; nz < 4; ++nz) {
            int ni = nb + nz;
            float4 pi = pred[base4 + ni * 2];
            float3 qi = cellpos(pi, ni);
            float d2 = dist2(pj, qi);
            bool prec = (pi.w > p.w) || ((pi.w == p.w) && (ni < pn));
            if ((pi.w > 0.5f) && (d2 < se) && prec) c++;
        }
    }
    return c;
}

// exact keep decision of slice-local point k (suppression on top of restrain),
// reading GLOBAL pred. Only called from the rare fallback path.
__device__ __noinline__ bool keep_of(const float4* __restrict__ pred,
                                     int base4, int k, float se) {
#pragma clang fp contract(off)
    float4 p = pred[base4 + k * 2];
    if (!(p.w > 0.5f)) return false;
    float3 pj = cellpos(p, k);
    int gx = k >> 7, gy = (k >> 2) & 31;
    for (int q = 0; q < 9; ++q) {
        int nx = gx + q / 3 - 1, ny = gy + q % 3 - 1;
        if ((unsigned)nx > 31u || (unsigned)ny > 31u) continue;
        int nb = nx * 128 + ny * 4;
        for (int nz = 0; nz < 4; ++nz) {
            int ni = nb + nz;
            float4 pi = pred[base4 + ni * 2];
            float3 qi = cellpos(pi, ni);
            float d2 = dist2(pj, qi);
            bool prec = (pi.w > p.w) || ((pi.w == p.w) && (ni < k));
            if ((pi.w > 0.5f) && (d2 < se) && prec &&
                restrain_of(pred, base4, ni, se) == 0u)
                return false;
        }
    }
    return true;
}

// ---------------------------------------------------------------------------
// Single fused kernel. One block per (s, gx, gy-quarter): 4*32*4 = 512 blocks,
// 512 threads -> 2 blocks/CU, 16 waves/CU.
// Stage : pred window [gx-4,gx+4] x [gy0-4,gy0+11] x z (9x16x4=576) -> LDS,
//         position pre-projected, conf in .w; OOB cells get conf=-1 which
//         every later predicate rejects, so phase loops are bounds-check-free.
// Phase A: restrain over 7x14x4=392 -> LDS uchar (z+-1 comps only).
// Phase B: keep over 5x12x4=240 -> LDS uchar (z+-1); interior 32 rows write
//          p_pos / mask_p / keep.
// Phase C: match (both variants) for the 32 interior rows, 16 threads/row,
//          5x5 xy window x full z from LDS, inline exact (global) fallback.
__global__ void __launch_bounds__(512, 4) k_all(const float4* __restrict__ pred,
                                                const float4* __restrict__ tgt,
                                                float* __restrict__ out,
                                                float s0, float s1) {
#pragma clang fp contract(off)
    __shared__ float4 pp[9 * 16 * 4];             // (pos.xyz, conf) 9216 B
    __shared__ unsigned char restr[7 * 14 * 4];   // 392
    __shared__ unsigned char keepl[5 * 12 * 4];   // 240
    int bid = blockIdx.x;
    int gy0 = (bid & 3) << 3, gx = (bid >> 2) & 31, s = bid >> 7;
    int b = s >> 1, e = s & 1;
    int base4 = b * 8192 + e;
    float se = (s & 1) ? s1 : s0;
    int t = (int)threadIdx.x;

    // phase-C row of this thread, target row prefetched at entry so the
    // global latency hides under stage/A/B.
    int rr = t >> 4, hh = t & 15;
    int gyy_c = rr >> 2, z_c = rr & 3;
    int n_c = (gx << 7) + ((gy0 + gyy_c) << 2) + z_c;
    float4 t4 = tgt[base4 + n_c * 2];

    // ---- stage pred window -> LDS (i = ((rx*16)+ry)*4+z exactly = linear i)
    for (int i = t; i < 576; i += 512) {
        int rx = i >> 6, rem = i & 63, ry = rem >> 2, z = rem & 3;
        int px = gx + rx - 4, py = gy0 + ry - 4;
        float4 v = {0.0f, 0.0f, 0.0f, -1.0f};
        if ((unsigned)px < 32u && (unsigned)py < 32u) {
            int pn = px * 128 + py * 4 + z;
            float4 p = pred[base4 + pn * 2];
            float3 c = cellpos(p, pn);
            v.x = c.x; v.y = c.y; v.z = c.z; v.w = p.w;
        }
        pp[i] = v;
    }
    __syncthreads();

    // ---- phase A: restrain halo (392 pts, 1/thread), z+-1 comps
    if (t < 392) {
        int ax = t / 56, rem = t - ax * 56, ay = rem >> 2, z = rem & 3;
        int px = gx + ax - 3, py = gy0 + ay - 3;
        float4 p = pp[((ax + 1) * 16 + (ay + 1)) * 4 + z];
        unsigned c = 0;
        if (p.w > 0.5f) {                          // OOB center: conf=-1 -> skip
            int pn = px * 128 + py * 4 + z;
            float3 pj = {p.x, p.y, p.z};
#pragma unroll
            for (int q = 0; q < 9; ++q) {
                int dx = q / 3 - 1, dy = q % 3 - 1;
                int nb = (px + dx) * 128 + (py + dy) * 4;
                const float4* pc = &pp[((ax + 1 + dx) * 16 + (ay + 1 + dy)) * 4];
#pragma unroll
                for (int dz = -1; dz <= 1; ++dz) {
                    int nz = z + dz;
                    int nzc = nz < 0 ? 0 : (nz > 3 ? 3 : nz);
                    float4 pi = pc[nzc];
                    int ni = nb + nz;
                    float3 qi = {pi.x, pi.y, pi.z};
                    float d2 = dist2(pj, qi);
                    bool zok = (unsigned)nz < 4u;
                    bool prec = (pi.w > p.w) || ((pi.w == p.w) && (ni < pn));
                    if (zok && (pi.w > 0.5f) && (d2 < se) && prec) c++;
                }
            }
        }
        restr[t] = (unsigned char)c;               // max 27, fits uchar
    }
    __syncthreads();

    // ---- phase B: keep halo (240 pts, 1/thread), z+-1; interior writes out
    if (t < 240) {
        int kx = t / 48, rem = t - kx * 48, ky = rem >> 2, z = rem & 3;
        int px = gx + kx - 2, py = gy0 + ky - 2;
        float4 p = pp[((kx + 2) * 16 + (ky + 2)) * 4 + z];
        bool valid = p.w > 0.5f;
        int pn = px * 128 + py * 4 + z;
        unsigned any = 0;
        if (valid) {
            float3 pj = {p.x, p.y, p.z};
#pragma unroll
            for (int q = 0; q < 9; ++q) {
                int dx = q / 3 - 1, dy = q % 3 - 1;
                int nb = (px + dx) * 128 + (py + dy) * 4;
                const float4* pc = &pp[((kx + 2 + dx) * 16 + (ky + 2 + dy)) * 4];
                const unsigned char* lr =
                    &restr[((kx + 1 + dx) * 14 + (ky + 1 + dy)) * 4];
#pragma unroll
                for (int dz = -1; dz <= 1; ++dz) {
                    int nz = z + dz;
                    int nzc = nz < 0 ? 0 : (nz > 3 ? 3 : nz);
                    float4 pi = pc[nzc];
                    int ni = nb + nz;
                    float3 qi = {pi.x, pi.y, pi.z};
                    float d2 = dist2(pj, qi);
                    bool zok = (unsigned)nz < 4u;
                    bool prec = (pi.w > p.w) || ((pi.w == p.w) && (ni < pn));
                    if (zok && (pi.w > 0.5f) && (lr[nzc] == 0) && (d2 < se) && prec)
                        any = 1u;
                }
            }
        }
        bool keep = valid && (any == 0);
        keepl[t] = keep ? 1 : 0;
        if (kx == 2 && ky >= 2 && ky < 10) {       // interior: always in-bounds
            int row = s * NPT + pn;
            out[O_PPOS + row * 3 + 0] = p.x;
            out[O_PPOS + row * 3 + 1] = p.y;
            out[O_PPOS + row * 3 + 2] = p.z;
            out[O_MASKP + row] = valid ? 1.0f : 0.0f;
            out[O_KEEP + row]  = keep ? 1.0f : 0.0f;
        }
    }
    __syncthreads();

    // ---- phase C: match, 32 rows x 16 threads
    int gyy = gyy_c, z = z_c, h = hh;
    int gy = gy0 + gyy;
    int n = n_c;
    int row = s * NPT + n;
    float3 tj = cellpos(t4, n);
    bool tv = t4.w > 0.5f;
    if (h == 0) {
        out[O_TPOS + row * 3 + 0] = tj.x;
        out[O_TPOS + row * 3 + 1] = tj.y;
        out[O_TPOS + row * 3 + 2] = tj.z;
        out[O_MASKT + row] = tv ? 1.0f : 0.0f;
    }
    if (!tv) {   // group-uniform early out (all-inf row -> masks 0, idx 0)
        if (h == 0) {
            out[O_TPT + row] = 0.0f; out[O_TPTN + row] = 0.0f;
            out[O_TPP + row] = 0.0f; out[O_TPPN + row] = 0.0f;
        }
        return;
    }
    unsigned long long bs = ~0ull, bn = ~0ull;
    unsigned as_ = 0, an_ = 0;
#pragma unroll
    for (int pass = 0; pass < 2; ++pass) {
        int q = pass * 16 + h;                     // pass0: h, pass1: h+16 (h<9)
        if (q > 24) continue;
        int dx = q / 5 - 2, dy = q % 5 - 2;
        int nb = (gx + dx) * 128 + (gy + dy) * 4;
        const float4* pc = &pp[((dx + 4) * 16 + (gyy + dy + 4)) * 4];
        const unsigned char* lk = &keepl[((dx + 2) * 12 + (gyy + dy + 2)) * 4];
#pragma unroll
        for (int nz = 0; nz < 4; ++nz) {
            float4 pi = pc[nz];
            int ni = nb + nz;
            float3 qi = {pi.x, pi.y, pi.z};
            float d2 = dist2(tj, qi);
            float dist = sqrtf(d2);
            unsigned long long enc =
                ((unsigned long long)__float_as_uint(dist) << 32) | (unsigned)ni;
            if (pi.w > 0.5f) { if (enc < bs) bs = enc; if (d2 < se) as_ = 1u; }
            if (lk[nz]) { if (enc < bn) bn = enc; if (d2 < se) an_ = 1u; }
        }
    }
    for (int m = 1; m < 16; m <<= 1) {             // combine across the 16-group
        unsigned long long o = shfl_xor_u64(bs, m); if (o < bs) bs = o;
        o = shfl_xor_u64(bn, m); if (o < bn) bn = o;
        as_ |= __shfl_xor(as_, m);
        an_ |= __shfl_xor(an_, m);
    }
    // empty best -> hi word 0xFFFFFFFF = NaN -> compare false -> fallback
    bool acc_s = __uint_as_float((unsigned)(bs >> 32)) < GUARD;
    bool acc_n = __uint_as_float((unsigned)(bn >> 32)) < GUARD;
    if (!(acc_s && acc_n)) {
        // exact full-row fallback by this 16-group (p ~ 1e-11, never observed;
        // bit-equal to window result when the window would have accepted).
        unsigned long long fs = ~0ull, fn = ~0ull;
        for (int k = h; k < NPT; k += 16) {
            float4 pi = pred[base4 + k * 2];
            float3 qi = cellpos(pi, k);
            float d2 = dist2(tj, qi);
            float dist = sqrtf(d2);
            unsigned long long enc =
                ((unsigned long long)__float_as_uint(dist) << 32) | (unsigned)k;
            if (pi.w > 0.5f && enc < fs) fs = enc;
            if (enc < fn && keep_of(pred, base4, k, se)) fn = enc;
        }
        for (int m = 1; m < 16; m <<= 1) {
            unsigned long long o = shfl_xor_u64(fs, m); if (o < fs) fs = o;
            o = shfl_xor_u64(fn, m); if (o < fn) fn = o;
        }
        bs = fs; bn = fn;
    }
    if (h == 0) {
        out[O_TPT + row]  = as_ ? 1.0f : 0.0f;
        out[O_TPTN + row] = an_ ? 1.0f : 0.0f;
        out[O_TPP + row]  = (float)((bs == ~0ull) ? 0u : (unsigned)(bs & 0xffffffffull));
        out[O_TPPN + row] = (float)((bn == ~0ull) ? 0u : (unsigned)(bn & 0xffffffffull));
    }
}

// ---------------------------------------------------------------------------
// host: smallest f with sqrtf(f) >= t, so (d2 < f) <=> (sqrtf(d2) < t) bit-exactly.
static float sq_boundary(float t) {
    float f = (float)((double)t * (double)t);
    while (sqrtf(f) >= t) f = nextafterf(f, 0.0f);
    while (sqrtf(f) < t)  f = nextafterf(f, __builtin_inff());
    return f;
}

extern "C" void kernel_launch(void* const* d_in, const int* in_sizes, int n_in,
                              void* d_out, int out_size, void* d_ws, size_t ws_size,
                              hipStream_t stream) {
    (void)in_sizes; (void)n_in; (void)out_size; (void)d_ws; (void)ws_size;
    const float4* pred = (const float4*)d_in[0];
    const float4* tgt  = (const float4*)d_in[1];
    float* out = (float*)d_out;

    float s0 = sq_boundary(0.74f);    // ELE_D[0]
    float s1 = sq_boundary(0.528f);   // ELE_D[1]

    k_all<<<dim3(512), dim3(512), 0, stream>>>(pred, tgt, out, s0, s1);
}